// Round 3
// baseline (1881.440 us; speedup 1.0000x reference)
//
#include <hip/hip_runtime.h>
#include <hip/hip_bf16.h>

#define NN   100000
#define EE   3200000
#define INF  512
#define HIDF 256
#define OUTF 64
#define KSTEPS 10

typedef __attribute__((ext_vector_type(8))) short short8;
typedef __attribute__((ext_vector_type(4))) float floatx4;
typedef __attribute__((ext_vector_type(4))) float f32x4;
typedef unsigned short ushort_t;

static __device__ inline short bf2s(__hip_bfloat16 h) {
    return __builtin_bit_cast(short, h);
}

// manual round-to-nearest-even f32 -> bf16 (finite inputs)
static __device__ inline unsigned short f2bf(float f) {
    unsigned u = __float_as_uint(f);
    unsigned r = (u + 0x7FFFu + ((u >> 16) & 1u)) >> 16;
    return (unsigned short)r;
}

static __device__ inline float b2f(unsigned short u) {
    return __uint_as_float(((unsigned)u) << 16);
}

// ---------------- setup kernels ----------------

__global__ void zero_kernel(int* p, int n) {
    int i = blockIdx.x * 256 + threadIdx.x;
    if (i < n) p[i] = 0;
}

__global__ void count_kernel(const int* __restrict__ ei, int* __restrict__ counts) {
    int e = blockIdx.x * 256 + threadIdx.x;
    if (e < EE) atomicAdd(&counts[ei[EE + e]], 1);
}

__global__ void dinv_kernel(const int* __restrict__ counts, float* __restrict__ dinv) {
    int i = blockIdx.x * 256 + threadIdx.x;
    if (i < NN) dinv[i] = rsqrtf((float)(counts[i] + 1));  // +1 self loop
}

// chunk=256 exclusive scan, per-block
__global__ void scan1(const int* __restrict__ counts, int* __restrict__ offs,
                      int* __restrict__ partial) {
    __shared__ int s[256];
    int tid = threadIdx.x;
    int i = blockIdx.x * 256 + tid;
    int v = (i < NN) ? counts[i] : 0;
    s[tid] = v;
    __syncthreads();
    for (int d = 1; d < 256; d <<= 1) {
        int t = (tid >= d) ? s[tid - d] : 0;
        __syncthreads();
        s[tid] += t;
        __syncthreads();
    }
    if (i < NN) offs[i] = s[tid] - v;     // exclusive within block
    if (tid == 255) partial[blockIdx.x] = s[255];
}

__global__ void scan2(int* partial, int nblocks) {
    __shared__ int s[512];
    int tid = threadIdx.x;
    int v = (tid < nblocks) ? partial[tid] : 0;
    s[tid] = v;
    __syncthreads();
    for (int d = 1; d < 512; d <<= 1) {
        int t = (tid >= d) ? s[tid - d] : 0;
        __syncthreads();
        s[tid] += t;
        __syncthreads();
    }
    if (tid < nblocks) partial[tid] = s[tid] - v;  // exclusive block bases
}

__global__ void scan3(int* __restrict__ offs, const int* __restrict__ partial) {
    int i = blockIdx.x * 256 + threadIdx.x;
    if (i < NN) offs[i] += partial[i >> 8];
    else if (i == NN) offs[NN] = EE;
}

// countdown-fill: reuses counts[] as cursor (counts destroyed here)
__global__ void fill_kernel(const int* __restrict__ ei, const int* __restrict__ offs,
                            int* __restrict__ counts, int* __restrict__ srcIdx) {
    int e = blockIdx.x * 256 + threadIdx.x;
    if (e >= EE) return;
    int r = ei[e];        // source (gathered from)
    int c = ei[EE + e];   // target (aggregated into)
    int old = atomicSub(&counts[c], 1);
    srcIdx[offs[c] + old - 1] = r;
}

// pack W1 into per-lane MFMA B-fragment order:
// dst[((kk*16+t)*64 + q*16 + l)*8 + jj] = bf16(W1[kk*32+q*8+jj][t*16+l])
__global__ void pack_w1(const float* __restrict__ W1, short* __restrict__ W1p) {
    int id = blockIdx.x * 256 + threadIdx.x;
    if (id >= INF * HIDF) return;
    int jj = id & 7, l = (id >> 3) & 15, q = (id >> 7) & 3, t = (id >> 9) & 15, kk = id >> 13;
    int k = kk * 32 + q * 8 + jj, n = t * 16 + l;
    W1p[id] = (short)f2bf(W1[k * HIDF + n]);
}

__global__ void pack_w2(const float* __restrict__ W2, short* __restrict__ W2p) {
    int id = blockIdx.x * 256 + threadIdx.x;
    if (id >= HIDF * OUTF) return;
    int jj = id & 7, l = (id >> 3) & 15, q = (id >> 7) & 3, t = (id >> 9) & 3, kk = id >> 11;
    int k = kk * 32 + q * 8 + jj, n = t * 16 + l;
    W2p[id] = (short)f2bf(W2[k * OUTF + n]);
}

// ---------------- fused MLP: h = relu(x@W1+b1)@W2+b2 ----------------
// writes z0 = bf16(dinv*h) in SLAB layout z0[slab][node][16], out = temp[0]*h

__global__ __launch_bounds__(256) void mlp_kernel(
    const float* __restrict__ x, const short* __restrict__ W1p,
    const short* __restrict__ W2p, const float* __restrict__ b1,
    const float* __restrict__ b2, const float* __restrict__ temp,
    const float* __restrict__ dinv,
    ushort_t* __restrict__ z0, float* __restrict__ out) {

    __shared__ __align__(16) short hlds[64][HIDF + 8];

    int tid = threadIdx.x;
    int wave = tid >> 6, lane = tid & 63;
    int l16 = lane & 15, quad = lane >> 4;
    int brow = blockIdx.x * 64;

    const floatx4 zf = {0.f, 0.f, 0.f, 0.f};
    floatx4 acc[4][4];
#pragma unroll
    for (int mi = 0; mi < 4; mi++)
#pragma unroll
        for (int j = 0; j < 4; j++) acc[mi][j] = zf;

    // row base pointers (clamped for tail block; stores masked later)
    const float* rp[4];
#pragma unroll
    for (int mi = 0; mi < 4; mi++) {
        int row = brow + mi * 16 + l16;
        if (row > NN - 1) row = NN - 1;
        rp[mi] = x + (size_t)row * INF + quad * 8;
    }

    // GEMM1: rows [brow,brow+64) x cols [wave*64, wave*64+64), K=512
    for (int kk = 0; kk < 16; kk++) {
        short8 a[4];
#pragma unroll
        for (int mi = 0; mi < 4; mi++) {
            const float4* ap = reinterpret_cast<const float4*>(rp[mi] + kk * 32);
            float4 f0 = ap[0];
            float4 f1 = ap[1];
            __hip_bfloat162 q0 = __float22bfloat162_rn(make_float2(f0.x, f0.y));
            __hip_bfloat162 q1 = __float22bfloat162_rn(make_float2(f0.z, f0.w));
            __hip_bfloat162 q2 = __float22bfloat162_rn(make_float2(f1.x, f1.y));
            __hip_bfloat162 q3 = __float22bfloat162_rn(make_float2(f1.z, f1.w));
            short8 av;
            av[0] = bf2s(q0.x); av[1] = bf2s(q0.y);
            av[2] = bf2s(q1.x); av[3] = bf2s(q1.y);
            av[4] = bf2s(q2.x); av[5] = bf2s(q2.y);
            av[6] = bf2s(q3.x); av[7] = bf2s(q3.y);
            a[mi] = av;
        }
        short8 b[4];
#pragma unroll
        for (int j = 0; j < 4; j++) {
            int t = wave * 4 + j;
            b[j] = *reinterpret_cast<const short8*>(
                W1p + (((size_t)(kk * 16 + t) * 64 + quad * 16 + l16) << 3));
        }
#pragma unroll
        for (int mi = 0; mi < 4; mi++)
#pragma unroll
            for (int j = 0; j < 4; j++)
                acc[mi][j] = __builtin_amdgcn_mfma_f32_16x16x32_bf16(a[mi], b[j], acc[mi][j], 0, 0, 0);
    }

    // bias + relu -> LDS (bf16), C-layout: D[row=quad*4+r][col=l16]
#pragma unroll
    for (int j = 0; j < 4; j++) {
        float bj = b1[wave * 64 + j * 16 + l16];
#pragma unroll
        for (int mi = 0; mi < 4; mi++)
#pragma unroll
            for (int r = 0; r < 4; r++) {
                float v = acc[mi][j][r] + bj;
                v = fmaxf(v, 0.f);
                hlds[mi * 16 + quad * 4 + r][wave * 64 + j * 16 + l16] = (short)f2bf(v);
            }
    }
    __syncthreads();

    // GEMM2: wave handles rows [wave*16, wave*16+16) x 64 out cols, K=256
    floatx4 acc2[4];
#pragma unroll
    for (int j = 0; j < 4; j++) acc2[j] = zf;

#pragma unroll
    for (int kk = 0; kk < 8; kk++) {
        short8 a2 = *reinterpret_cast<const short8*>(&hlds[wave * 16 + l16][kk * 32 + quad * 8]);
#pragma unroll
        for (int j = 0; j < 4; j++) {
            short8 bb = *reinterpret_cast<const short8*>(
                W2p + (((size_t)(kk * 4 + j) * 64 + quad * 16 + l16) << 3));
            acc2[j] = __builtin_amdgcn_mfma_f32_16x16x32_bf16(a2, bb, acc2[j], 0, 0, 0);
        }
    }

    float t0 = temp[0];
#pragma unroll
    for (int j = 0; j < 4; j++) {
        float bb = b2[j * 16 + l16];
#pragma unroll
        for (int r = 0; r < 4; r++) {
            int row = brow + wave * 16 + quad * 4 + r;
            if (row < NN) {
                float v = acc2[j][r] + bb;
                out[(size_t)row * 64 + j * 16 + l16] = t0 * v;
                // slab layout: z0[slab j][row][l16]
                z0[(size_t)j * (NN * 16) + (size_t)row * 16 + l16] = f2bf(dinv[row] * v);
            }
        }
    }
}

// ---------------- propagation: feature-slab decomposition ----------------
// z stored as z[slab][node][16] bf16 (32 B per node per slab, slab = 3.2 MB).
// slab = blockIdx.x & 3: with round-robin block->XCD dispatch, each XCD's L2
// sees exactly ONE slab (bid%8 == xcd  =>  bid&3 == xcd&3) -> gathers hit L2.
// Coverage is mapping-independent (bid enumerates all (chunk,slab) pairs).
// Wave layout: 4 nodes x 8 edge-slots x 2 feature-halves (16B dwordx4/lane).
// Streams (srcIdx, hid) are non-temporal so they don't evict the slab.

#define BLO(u) __uint_as_float((u) << 16)
#define BHI(u) __uint_as_float((u) & 0xFFFF0000u)
#define ACC8(v)                      \
    do {                             \
        a0 += BLO((v).x);            \
        a1 += BHI((v).x);            \
        a2 += BLO((v).y);            \
        a3 += BHI((v).y);            \
        a4 += BLO((v).z);            \
        a5 += BHI((v).z);            \
        a6 += BLO((v).w);            \
        a7 += BHI((v).w);            \
    } while (0)

__global__ __launch_bounds__(256, 8) void prop_kernel(
    const int* __restrict__ srcIdx, const int* __restrict__ offs,
    const float* __restrict__ dinv, const ushort_t* __restrict__ z,
    ushort_t* __restrict__ zn, float* __restrict__ hid,
    const float* __restrict__ temp, int k, int write_z) {

    int bid = blockIdx.x;             // grid = (NN/16)*4 = 25000
    int slab = bid & 3;
    int chunk = bid >> 2;             // 0..6249
    int lane = threadIdx.x & 63;
    int wid = threadIdx.x >> 6;       // 4 waves
    int n = lane >> 4;                // node sub-group within wave (0..3)
    int g = (lane >> 1) & 7;          // edge slot (0..7)
    int q = lane & 1;                 // 16B half of the 32B slab row

    int node = chunk * 16 + wid * 4 + n;   // < 100000 exactly (6250*16)

    const ushort_t* zs = z + (size_t)slab * (NN * 16);

    int beg = offs[node];
    int end = offs[node + 1];

    float a0 = 0.f, a1 = 0.f, a2 = 0.f, a3 = 0.f;
    float a4 = 0.f, a5 = 0.f, a6 = 0.f, a7 = 0.f;

    // self-loop term: only edge-slot 0 accumulates
    {
        uint4 v = reinterpret_cast<const uint4*>(zs + (size_t)node * 16)[q];
        if (g == 0) ACC8(v);
    }

    int e = beg;
    // main loop: 16 edges per node-subgroup per iter, 2 gathers in flight
    for (; e + 16 <= end; e += 16) {
        int s0 = __builtin_nontemporal_load(srcIdx + e + g);
        int s1 = __builtin_nontemporal_load(srcIdx + e + 8 + g);
        uint4 v0 = reinterpret_cast<const uint4*>(zs + (size_t)s0 * 16)[q];
        uint4 v1 = reinterpret_cast<const uint4*>(zs + (size_t)s1 * 16)[q];
        ACC8(v0);
        ACC8(v1);
    }
    // tail: 8 edges at a time; inactive lanes issue NO memory request
    for (; e < end; e += 8) {
        int ee = e + g;
        int cl = (ee < end) ? ee : (end - 1);
        int s = __builtin_nontemporal_load(srcIdx + cl);
        if (ee < end) {
            uint4 v = reinterpret_cast<const uint4*>(zs + (size_t)s * 16)[q];
            ACC8(v);
        }
    }

    // butterfly reduce across the 8 edge-slots (lane bits 1..3, stays in
    // the 16-lane node sub-group)
#pragma unroll
    for (int m = 2; m <= 8; m <<= 1) {
        a0 += __shfl_xor(a0, m);
        a1 += __shfl_xor(a1, m);
        a2 += __shfl_xor(a2, m);
        a3 += __shfl_xor(a3, m);
        a4 += __shfl_xor(a4, m);
        a5 += __shfl_xor(a5, m);
        a6 += __shfl_xor(a6, m);
        a7 += __shfl_xor(a7, m);
    }

    float dv = dinv[node];
    float tk = temp[k];
    float c0 = dv * a0, c1 = dv * a1, c2 = dv * a2, c3 = dv * a3;
    float c4 = dv * a4, c5 = dv * a5, c6 = dv * a6, c7 = dv * a7;

    if (g == 0) {
        // hid RMW: 16 floats per node per slab = exactly one 64B line
        float* hp = hid + (size_t)node * 64 + slab * 16 + q * 8;
        f32x4 h0 = __builtin_nontemporal_load(reinterpret_cast<f32x4*>(hp));
        f32x4 h1 = __builtin_nontemporal_load(reinterpret_cast<f32x4*>(hp) + 1);
        h0[0] += tk * c0; h0[1] += tk * c1; h0[2] += tk * c2; h0[3] += tk * c3;
        h1[0] += tk * c4; h1[1] += tk * c5; h1[2] += tk * c6; h1[3] += tk * c7;
        __builtin_nontemporal_store(h0, reinterpret_cast<f32x4*>(hp));
        __builtin_nontemporal_store(h1, reinterpret_cast<f32x4*>(hp) + 1);
        if (write_z) {
            uint4 u;
            u.x = (unsigned)f2bf(dv * c0) | ((unsigned)f2bf(dv * c1) << 16);
            u.y = (unsigned)f2bf(dv * c2) | ((unsigned)f2bf(dv * c3) << 16);
            u.z = (unsigned)f2bf(dv * c4) | ((unsigned)f2bf(dv * c5) << 16);
            u.w = (unsigned)f2bf(dv * c6) | ((unsigned)f2bf(dv * c7) << 16);
            reinterpret_cast<uint4*>(zn + (size_t)slab * (NN * 16) +
                                     (size_t)node * 16)[q] = u;
        }
    }
}

// ---------------- launch ----------------

extern "C" void kernel_launch(void* const* d_in, const int* in_sizes, int n_in,
                              void* d_out, int out_size, void* d_ws, size_t ws_size,
                              hipStream_t stream) {
    const float* x    = (const float*)d_in[0];
    const int*   ei   = (const int*)d_in[1];   // [2,E] int32 (harness converts int64)
    const float* W1   = (const float*)d_in[2];
    const float* b1   = (const float*)d_in[3];
    const float* W2   = (const float*)d_in[4];
    const float* b2   = (const float*)d_in[5];
    const float* temp = (const float*)d_in[6];
    float* out = (float*)d_out;

    char* p = (char*)d_ws;
    auto carve = [&](size_t bytes) -> char* {
        char* r = p;
        p += (bytes + 255) & ~(size_t)255;
        return r;
    };
    ushort_t* zA   = (ushort_t*)carve(sizeof(ushort_t) * (size_t)NN * 64);
    ushort_t* zB   = (ushort_t*)carve(sizeof(ushort_t) * (size_t)NN * 64);
    int* srcIdx    = (int*)carve(sizeof(int) * (size_t)EE);
    int* counts    = (int*)carve(sizeof(int) * NN);
    int* offs      = (int*)carve(sizeof(int) * (NN + 1));
    int* partial   = (int*)carve(sizeof(int) * 512);
    float* dinv    = (float*)carve(sizeof(float) * NN);
    short* W1p     = (short*)carve(sizeof(short) * INF * HIDF);
    short* W2p     = (short*)carve(sizeof(short) * HIDF * OUTF);

    const int NB = (NN + 255) / 256;      // 391

    zero_kernel<<<NB, 256, 0, stream>>>(counts, NN);
    pack_w1<<<(INF * HIDF + 255) / 256, 256, 0, stream>>>(W1, W1p);
    pack_w2<<<(HIDF * OUTF + 255) / 256, 256, 0, stream>>>(W2, W2p);

    count_kernel<<<EE / 256, 256, 0, stream>>>(ei, counts);
    dinv_kernel<<<NB, 256, 0, stream>>>(counts, dinv);
    scan1<<<NB, 256, 0, stream>>>(counts, offs, partial);
    scan2<<<1, 512, 0, stream>>>(partial, NB);
    scan3<<<(NN + 256) / 256, 256, 0, stream>>>(offs, partial);
    fill_kernel<<<EE / 256, 256, 0, stream>>>(ei, offs, counts, srcIdx);

    mlp_kernel<<<(NN + 63) / 64, 256, 0, stream>>>(x, W1p, W2p, b1, b2, temp, dinv, zA, out);

    ushort_t* a = zA;
    ushort_t* b = zB;
    for (int k = 1; k <= KSTEPS; k++) {
        prop_kernel<<<(NN / 16) * 4, 256, 0, stream>>>(srcIdx, offs, dinv, a, b, out, temp, k,
                                                       (k < KSTEPS) ? 1 : 0);
        ushort_t* t = a; a = b; b = t;
    }
}

// Round 4
// 1443.493 us; speedup vs baseline: 1.3034x; 1.3034x over previous
//
#include <hip/hip_runtime.h>
#include <hip/hip_bf16.h>

#define NN   100000
#define EE   3200000
#define INF  512
#define HIDF 256
#define OUTF 64
#define KSTEPS 10

// binned fill: 7 bins of 16384 target nodes (2 MB srcIdx region per bin)
#define NBIN 7
#define BINSH 14

typedef __attribute__((ext_vector_type(8))) short short8;
typedef __attribute__((ext_vector_type(4))) float floatx4;
typedef unsigned short ushort_t;

static __device__ inline short bf2s(__hip_bfloat16 h) {
    return __builtin_bit_cast(short, h);
}

// manual round-to-nearest-even f32 -> bf16 (finite inputs)
static __device__ inline unsigned short f2bf(float f) {
    unsigned u = __float_as_uint(f);
    unsigned r = (u + 0x7FFFu + ((u >> 16) & 1u)) >> 16;
    return (unsigned short)r;
}

static __device__ inline float b2f(unsigned short u) {
    return __uint_as_float(((unsigned)u) << 16);
}

// ---------------- setup kernels ----------------

__global__ void zero_kernel(int* p, int n) {
    int i = blockIdx.x * 256 + threadIdx.x;
    if (i < n) p[i] = 0;
}

__global__ void count_kernel(const int* __restrict__ ei, int* __restrict__ counts) {
    int e = blockIdx.x * 256 + threadIdx.x;
    if (e < EE) atomicAdd(&counts[ei[EE + e]], 1);
}

__global__ void dinv_kernel(const int* __restrict__ counts, float* __restrict__ dinv) {
    int i = blockIdx.x * 256 + threadIdx.x;
    if (i < NN) dinv[i] = rsqrtf((float)(counts[i] + 1));  // +1 self loop
}

// chunk=256 exclusive scan, per-block
__global__ void scan1(const int* __restrict__ counts, int* __restrict__ offs,
                      int* __restrict__ partial) {
    __shared__ int s[256];
    int tid = threadIdx.x;
    int i = blockIdx.x * 256 + tid;
    int v = (i < NN) ? counts[i] : 0;
    s[tid] = v;
    __syncthreads();
    for (int d = 1; d < 256; d <<= 1) {
        int t = (tid >= d) ? s[tid - d] : 0;
        __syncthreads();
        s[tid] += t;
        __syncthreads();
    }
    if (i < NN) offs[i] = s[tid] - v;     // exclusive within block
    if (tid == 255) partial[blockIdx.x] = s[255];
}

__global__ void scan2(int* partial, int nblocks) {
    __shared__ int s[512];
    int tid = threadIdx.x;
    int v = (tid < nblocks) ? partial[tid] : 0;
    s[tid] = v;
    __syncthreads();
    for (int d = 1; d < 512; d <<= 1) {
        int t = (tid >= d) ? s[tid - d] : 0;
        __syncthreads();
        s[tid] += t;
        __syncthreads();
    }
    if (tid < nblocks) partial[tid] = s[tid] - v;  // exclusive block bases
}

__global__ void scan3(int* __restrict__ offs, const int* __restrict__ partial) {
    int i = blockIdx.x * 256 + threadIdx.x;
    if (i < NN) offs[i] += partial[i >> 8];
    else if (i == NN) offs[NN] = EE;
}

// binOffs[b] = offs[b<<BINSH] (start of bin b's srcIdx region), binOffs[7]=EE.
// cursors = working copy mutated by bin_kernel.
__global__ void init_bins(const int* __restrict__ offs, int* __restrict__ binOffs,
                          int* __restrict__ cursors) {
    int t = threadIdx.x;
    if (t < NBIN + 1) {
        int v = (t < NBIN) ? offs[t << BINSH] : EE;
        binOffs[t] = v;
        if (t < NBIN) cursors[t] = v;
    }
}

// pass A: partition edges by target-high-bits into NBIN contiguous regions.
// Per 256-edge round, LDS-bin then flush each bin as one contiguous burst
// (overflow impossible: <=256 edges/round = per-bin LDS capacity).
// Edge packed into 4B: src (17b) << 14 | (c & 16383).
__global__ __launch_bounds__(256) void bin_kernel(
    const int* __restrict__ ei, int* __restrict__ cursors,
    unsigned* __restrict__ packed) {
    __shared__ int lcount[NBIN];
    __shared__ int lbase[NBIN];
    __shared__ unsigned lbuf[NBIN][256];
    int tid = threadIdx.x;
    for (int r = blockIdx.x; r < EE / 256; r += gridDim.x) {
        if (tid < NBIN) lcount[tid] = 0;
        __syncthreads();
        int e = r * 256 + tid;            // EE = 12500*256 exactly, no tail
        int src = ei[e];
        int c = ei[EE + e];
        int b = c >> BINSH;
        int slot = atomicAdd(&lcount[b], 1);
        lbuf[b][slot] = ((unsigned)src << BINSH) | (unsigned)(c & ((1 << BINSH) - 1));
        __syncthreads();
        if (tid < NBIN) lbase[tid] = atomicAdd(&cursors[tid], lcount[tid]);
        __syncthreads();
#pragma unroll
        for (int b2 = 0; b2 < NBIN; b2++) {
            int n = lcount[b2];
            int base = lbase[b2];
            for (int j = tid; j < n; j += 256)
                packed[base + j] = lbuf[b2][j];
        }
        __syncthreads();
    }
}

// pass B: countdown-fill from the BINNED stream. Scatter writes are now
// confined to the active bins' 2MB srcIdx regions -> the 16 writes per 64B
// line coalesce in L2 and each line goes to HBM once (vs 16x before).
// counts[] reused as cursor (destroyed here).
__global__ __launch_bounds__(256) void fill2_kernel(
    const unsigned* __restrict__ packed, const int* __restrict__ offs,
    int* __restrict__ counts, int* __restrict__ srcIdx,
    const int* __restrict__ binOffs) {
    __shared__ int bo[NBIN + 1];
    int tid = threadIdx.x;
    if (tid < NBIN + 1) bo[tid] = binOffs[tid];
    __syncthreads();
    int e = blockIdx.x * 256 + tid;       // grid = EE/256 exactly
    int b = 0;
#pragma unroll
    for (int i = 1; i < NBIN; i++) b += (e >= bo[i]) ? 1 : 0;
    unsigned p = packed[e];
    int c = (b << BINSH) | (int)(p & ((1u << BINSH) - 1));
    int r = (int)(p >> BINSH);
    int old = atomicSub(&counts[c], 1);
    srcIdx[offs[c] + old - 1] = r;
}

// pack W1 into per-lane MFMA B-fragment order:
// dst[((kk*16+t)*64 + q*16 + l)*8 + jj] = bf16(W1[kk*32+q*8+jj][t*16+l])
__global__ void pack_w1(const float* __restrict__ W1, short* __restrict__ W1p) {
    int id = blockIdx.x * 256 + threadIdx.x;
    if (id >= INF * HIDF) return;
    int jj = id & 7, l = (id >> 3) & 15, q = (id >> 7) & 3, t = (id >> 9) & 15, kk = id >> 13;
    int k = kk * 32 + q * 8 + jj, n = t * 16 + l;
    W1p[id] = (short)f2bf(W1[k * HIDF + n]);
}

__global__ void pack_w2(const float* __restrict__ W2, short* __restrict__ W2p) {
    int id = blockIdx.x * 256 + threadIdx.x;
    if (id >= HIDF * OUTF) return;
    int jj = id & 7, l = (id >> 3) & 15, q = (id >> 7) & 3, t = (id >> 9) & 3, kk = id >> 11;
    int k = kk * 32 + q * 8 + jj, n = t * 16 + l;
    W2p[id] = (short)f2bf(W2[k * OUTF + n]);
}

// ---------------- fused MLP: h = relu(x@W1+b1)@W2+b2 ----------------
// writes z0 = bf16(dinv*h) and out = temp[0]*h

__global__ __launch_bounds__(256) void mlp_kernel(
    const float* __restrict__ x, const short* __restrict__ W1p,
    const short* __restrict__ W2p, const float* __restrict__ b1,
    const float* __restrict__ b2, const float* __restrict__ temp,
    const float* __restrict__ dinv,
    ushort_t* __restrict__ z0, float* __restrict__ out) {

    __shared__ __align__(16) short hlds[64][HIDF + 8];

    int tid = threadIdx.x;
    int wave = tid >> 6, lane = tid & 63;
    int l16 = lane & 15, quad = lane >> 4;
    int brow = blockIdx.x * 64;

    const floatx4 zf = {0.f, 0.f, 0.f, 0.f};
    floatx4 acc[4][4];
#pragma unroll
    for (int mi = 0; mi < 4; mi++)
#pragma unroll
        for (int j = 0; j < 4; j++) acc[mi][j] = zf;

    // row base pointers (clamped for tail block; stores masked later)
    const float* rp[4];
#pragma unroll
    for (int mi = 0; mi < 4; mi++) {
        int row = brow + mi * 16 + l16;
        if (row > NN - 1) row = NN - 1;
        rp[mi] = x + (size_t)row * INF + quad * 8;
    }

    // GEMM1: rows [brow,brow+64) x cols [wave*64, wave*64+64), K=512
    for (int kk = 0; kk < 16; kk++) {
        short8 a[4];
#pragma unroll
        for (int mi = 0; mi < 4; mi++) {
            const float4* ap = reinterpret_cast<const float4*>(rp[mi] + kk * 32);
            float4 f0 = ap[0];
            float4 f1 = ap[1];
            __hip_bfloat162 q0 = __float22bfloat162_rn(make_float2(f0.x, f0.y));
            __hip_bfloat162 q1 = __float22bfloat162_rn(make_float2(f0.z, f0.w));
            __hip_bfloat162 q2 = __float22bfloat162_rn(make_float2(f1.x, f1.y));
            __hip_bfloat162 q3 = __float22bfloat162_rn(make_float2(f1.z, f1.w));
            short8 av;
            av[0] = bf2s(q0.x); av[1] = bf2s(q0.y);
            av[2] = bf2s(q1.x); av[3] = bf2s(q1.y);
            av[4] = bf2s(q2.x); av[5] = bf2s(q2.y);
            av[6] = bf2s(q3.x); av[7] = bf2s(q3.y);
            a[mi] = av;
        }
        short8 b[4];
#pragma unroll
        for (int j = 0; j < 4; j++) {
            int t = wave * 4 + j;
            b[j] = *reinterpret_cast<const short8*>(
                W1p + (((size_t)(kk * 16 + t) * 64 + quad * 16 + l16) << 3));
        }
#pragma unroll
        for (int mi = 0; mi < 4; mi++)
#pragma unroll
            for (int j = 0; j < 4; j++)
                acc[mi][j] = __builtin_amdgcn_mfma_f32_16x16x32_bf16(a[mi], b[j], acc[mi][j], 0, 0, 0);
    }

    // bias + relu -> LDS (bf16), C-layout: D[row=quad*4+r][col=l16]
#pragma unroll
    for (int j = 0; j < 4; j++) {
        float bj = b1[wave * 64 + j * 16 + l16];
#pragma unroll
        for (int mi = 0; mi < 4; mi++)
#pragma unroll
            for (int r = 0; r < 4; r++) {
                float v = acc[mi][j][r] + bj;
                v = fmaxf(v, 0.f);
                hlds[mi * 16 + quad * 4 + r][wave * 64 + j * 16 + l16] = (short)f2bf(v);
            }
    }
    __syncthreads();

    // GEMM2: wave handles rows [wave*16, wave*16+16) x 64 out cols, K=256
    floatx4 acc2[4];
#pragma unroll
    for (int j = 0; j < 4; j++) acc2[j] = zf;

#pragma unroll
    for (int kk = 0; kk < 8; kk++) {
        short8 a2 = *reinterpret_cast<const short8*>(&hlds[wave * 16 + l16][kk * 32 + quad * 8]);
#pragma unroll
        for (int j = 0; j < 4; j++) {
            short8 bb = *reinterpret_cast<const short8*>(
                W2p + (((size_t)(kk * 4 + j) * 64 + quad * 16 + l16) << 3));
            acc2[j] = __builtin_amdgcn_mfma_f32_16x16x32_bf16(a2, bb, acc2[j], 0, 0, 0);
        }
    }

    float t0 = temp[0];
#pragma unroll
    for (int j = 0; j < 4; j++) {
        float bb = b2[j * 16 + l16];
#pragma unroll
        for (int r = 0; r < 4; r++) {
            int row = brow + wave * 16 + quad * 4 + r;
            if (row < NN) {
                float v = acc2[j][r] + bb;
                size_t o = (size_t)row * 64 + j * 16 + l16;
                out[o] = t0 * v;
                z0[o] = f2bf(dinv[row] * v);
            }
        }
    }
}

// ---------------- propagation: one wave per target node ----------------
// Wide-gather layout: lane = (g, q), g = lane>>3 picks one of 8 edges per
// load instruction, q = lane&7 owns features q*8..q*8+7 (16B of bf16).
// Each lane loads dwordx4 (16B) per edge -> 8 edges per wave per VMEM instr,
// 2-deep unroll -> 2KB outstanding per wave.
// acc = z[self] + sum z[src]; cn = dinv*acc; hid += temp[k]*cn;
// z' = bf16(dinv*cn).

#define BLO(u) __uint_as_float((u) << 16)
#define BHI(u) __uint_as_float((u) & 0xFFFF0000u)
#define ACC8(v)                      \
    do {                             \
        a0 += BLO((v).x);            \
        a1 += BHI((v).x);            \
        a2 += BLO((v).y);            \
        a3 += BHI((v).y);            \
        a4 += BLO((v).z);            \
        a5 += BHI((v).z);            \
        a6 += BLO((v).w);            \
        a7 += BHI((v).w);            \
    } while (0)

__global__ __launch_bounds__(256, 8) void prop_kernel(
    const int* __restrict__ srcIdx, const int* __restrict__ offs,
    const float* __restrict__ dinv, const ushort_t* __restrict__ z,
    ushort_t* __restrict__ zn, float* __restrict__ hid,
    const float* __restrict__ temp, int k, int write_z) {

    int node = blockIdx.x * 4 + (threadIdx.x >> 6);   // NN = 4*25000 exactly
    int lane = threadIdx.x & 63;
    int g = lane >> 3;   // edge slot within the 8-edge group
    int q = lane & 7;    // feature octet

    int beg = __builtin_amdgcn_readfirstlane(offs[node]);
    int end = __builtin_amdgcn_readfirstlane(offs[node + 1]);

    float a0 = 0.f, a1 = 0.f, a2 = 0.f, a3 = 0.f;
    float a4 = 0.f, a5 = 0.f, a6 = 0.f, a7 = 0.f;

    // self-loop term: whole wave loads (line broadcast), only group 0 adds
    {
        uint4 v = reinterpret_cast<const uint4*>(z + ((size_t)node << 6))[q];
        if (g == 0) ACC8(v);
    }

    int e = beg;
    // main loop: 16 edges per iteration, 2 independent 16B gathers in flight
    for (; e + 16 <= end; e += 16) {
        int s0 = srcIdx[e + g];
        int s1 = srcIdx[e + 8 + g];
        uint4 v0 = reinterpret_cast<const uint4*>(z + ((size_t)s0 << 6))[q];
        uint4 v1 = reinterpret_cast<const uint4*>(z + ((size_t)s1 << 6))[q];
        ACC8(v0);
        ACC8(v1);
    }
    // tail: 8 edges at a time, clamp+predicate
    for (; e < end; e += 8) {
        int ee = e + g;
        int cl = (ee < end) ? ee : (end - 1);
        int s = srcIdx[cl];
        uint4 v = reinterpret_cast<const uint4*>(z + ((size_t)s << 6))[q];
        if (ee < end) ACC8(v);
    }

    // butterfly reduce across the 8 edge-groups (lane bits 3,4,5)
#pragma unroll
    for (int m = 8; m < 64; m <<= 1) {
        a0 += __shfl_xor(a0, m);
        a1 += __shfl_xor(a1, m);
        a2 += __shfl_xor(a2, m);
        a3 += __shfl_xor(a3, m);
        a4 += __shfl_xor(a4, m);
        a5 += __shfl_xor(a5, m);
        a6 += __shfl_xor(a6, m);
        a7 += __shfl_xor(a7, m);
    }

    float dv = dinv[node];
    float tk = temp[k];
    float c0 = dv * a0, c1 = dv * a1, c2 = dv * a2, c3 = dv * a3;
    float c4 = dv * a4, c5 = dv * a5, c6 = dv * a6, c7 = dv * a7;

    if (g == 0) {
        float* hp = hid + ((size_t)node << 6) + q * 8;
        float4 h0 = *reinterpret_cast<float4*>(hp);
        float4 h1 = *reinterpret_cast<float4*>(hp + 4);
        h0.x += tk * c0; h0.y += tk * c1; h0.z += tk * c2; h0.w += tk * c3;
        h1.x += tk * c4; h1.y += tk * c5; h1.z += tk * c6; h1.w += tk * c7;
        *reinterpret_cast<float4*>(hp) = h0;
        *reinterpret_cast<float4*>(hp + 4) = h1;
        if (write_z) {
            uint4 u;
            u.x = (unsigned)f2bf(dv * c0) | ((unsigned)f2bf(dv * c1) << 16);
            u.y = (unsigned)f2bf(dv * c2) | ((unsigned)f2bf(dv * c3) << 16);
            u.z = (unsigned)f2bf(dv * c4) | ((unsigned)f2bf(dv * c5) << 16);
            u.w = (unsigned)f2bf(dv * c6) | ((unsigned)f2bf(dv * c7) << 16);
            reinterpret_cast<uint4*>(zn + ((size_t)node << 6))[q] = u;
        }
    }
}

// ---------------- launch ----------------

extern "C" void kernel_launch(void* const* d_in, const int* in_sizes, int n_in,
                              void* d_out, int out_size, void* d_ws, size_t ws_size,
                              hipStream_t stream) {
    const float* x    = (const float*)d_in[0];
    const int*   ei   = (const int*)d_in[1];   // [2,E] int32 (harness converts int64)
    const float* W1   = (const float*)d_in[2];
    const float* b1   = (const float*)d_in[3];
    const float* W2   = (const float*)d_in[4];
    const float* b2   = (const float*)d_in[5];
    const float* temp = (const float*)d_in[6];
    float* out = (float*)d_out;

    char* p = (char*)d_ws;
    auto carve = [&](size_t bytes) -> char* {
        char* r = p;
        p += (bytes + 255) & ~(size_t)255;
        return r;
    };
    ushort_t* zA   = (ushort_t*)carve(sizeof(ushort_t) * (size_t)NN * 64);
    ushort_t* zB   = (ushort_t*)carve(sizeof(ushort_t) * (size_t)NN * 64);
    int* srcIdx    = (int*)carve(sizeof(int) * (size_t)EE);
    int* counts    = (int*)carve(sizeof(int) * NN);
    int* offs      = (int*)carve(sizeof(int) * (NN + 1));
    int* partial   = (int*)carve(sizeof(int) * 512);
    float* dinv    = (float*)carve(sizeof(float) * NN);
    short* W1p     = (short*)carve(sizeof(short) * INF * HIDF);
    short* W2p     = (short*)carve(sizeof(short) * HIDF * OUTF);
    int* binOffs   = (int*)carve(sizeof(int) * (NBIN + 1));
    int* cursors   = (int*)carve(sizeof(int) * NBIN);
    // packed binned edges alias zB: EE*4B == NN*64*2B, and packed is dead
    // before prop step 1 (the first writer of zB) runs.
    unsigned* packed = (unsigned*)zB;

    const int NB = (NN + 255) / 256;      // 391

    zero_kernel<<<NB, 256, 0, stream>>>(counts, NN);
    pack_w1<<<(INF * HIDF + 255) / 256, 256, 0, stream>>>(W1, W1p);
    pack_w2<<<(HIDF * OUTF + 255) / 256, 256, 0, stream>>>(W2, W2p);

    count_kernel<<<EE / 256, 256, 0, stream>>>(ei, counts);
    dinv_kernel<<<NB, 256, 0, stream>>>(counts, dinv);
    scan1<<<NB, 256, 0, stream>>>(counts, offs, partial);
    scan2<<<1, 512, 0, stream>>>(partial, NB);
    scan3<<<(NN + 256) / 256, 256, 0, stream>>>(offs, partial);

    init_bins<<<1, 64, 0, stream>>>(offs, binOffs, cursors);
    bin_kernel<<<1024, 256, 0, stream>>>(ei, cursors, packed);
    fill2_kernel<<<EE / 256, 256, 0, stream>>>(packed, offs, counts, srcIdx, binOffs);

    mlp_kernel<<<(NN + 63) / 64, 256, 0, stream>>>(x, W1p, W2p, b1, b2, temp, dinv, zA, out);

    ushort_t* a = zA;
    ushort_t* b = zB;
    for (int k = 1; k <= KSTEPS; k++) {
        prop_kernel<<<NN / 4, 256, 0, stream>>>(srcIdx, offs, dinv, a, b, out, temp, k,
                                                (k < KSTEPS) ? 1 : 0);
        ushort_t* t = a; a = b; b = t;
    }
}

// Round 6
// 1267.944 us; speedup vs baseline: 1.4839x; 1.1385x over previous
//
#include <hip/hip_runtime.h>
#include <hip/hip_bf16.h>

#define NN   100000
#define EE   3200000
#define INF  512
#define HIDF 256
#define OUTF 64
#define KSTEPS 10

typedef __attribute__((ext_vector_type(8))) short short8;
typedef __attribute__((ext_vector_type(4))) float floatx4;
typedef unsigned short ushort_t;

static __device__ inline short bf2s(__hip_bfloat16 h) {
    return __builtin_bit_cast(short, h);
}

// manual round-to-nearest-even f32 -> bf16 (finite inputs)
static __device__ inline unsigned short f2bf(float f) {
    unsigned u = __float_as_uint(f);
    unsigned r = (u + 0x7FFFu + ((u >> 16) & 1u)) >> 16;
    return (unsigned short)r;
}

static __device__ inline float b2f(unsigned short u) {
    return __uint_as_float(((unsigned)u) << 16);
}

// ---------------- setup kernels ----------------

__global__ void zero_kernel(int* p, int n) {
    int i = blockIdx.x * 256 + threadIdx.x;
    if (i < n) p[i] = 0;
}

__global__ void count_kernel(const int* __restrict__ ei, int* __restrict__ counts) {
    int e = blockIdx.x * 256 + threadIdx.x;
    if (e < EE) atomicAdd(&counts[ei[EE + e]], 1);
}

__global__ void dinv_kernel(const int* __restrict__ counts, float* __restrict__ dinv) {
    int i = blockIdx.x * 256 + threadIdx.x;
    if (i < NN) dinv[i] = rsqrtf((float)(counts[i] + 1));  // +1 self loop
}

// chunk=256 exclusive scan, per-block
__global__ void scan1(const int* __restrict__ counts, int* __restrict__ offs,
                      int* __restrict__ partial) {
    __shared__ int s[256];
    int tid = threadIdx.x;
    int i = blockIdx.x * 256 + tid;
    int v = (i < NN) ? counts[i] : 0;
    s[tid] = v;
    __syncthreads();
    for (int d = 1; d < 256; d <<= 1) {
        int t = (tid >= d) ? s[tid - d] : 0;
        __syncthreads();
        s[tid] += t;
        __syncthreads();
    }
    if (i < NN) offs[i] = s[tid] - v;     // exclusive within block
    if (tid == 255) partial[blockIdx.x] = s[255];
}

__global__ void scan2(int* partial, int nblocks) {
    __shared__ int s[512];
    int tid = threadIdx.x;
    int v = (tid < nblocks) ? partial[tid] : 0;
    s[tid] = v;
    __syncthreads();
    for (int d = 1; d < 512; d <<= 1) {
        int t = (tid >= d) ? s[tid - d] : 0;
        __syncthreads();
        s[tid] += t;
        __syncthreads();
    }
    if (tid < nblocks) partial[tid] = s[tid] - v;  // exclusive block bases
}

__global__ void scan3(int* __restrict__ offs, const int* __restrict__ partial) {
    int i = blockIdx.x * 256 + threadIdx.x;
    if (i < NN) offs[i] += partial[i >> 8];
    else if (i == NN) offs[NN] = EE;
}

// countdown-fill: reuses counts[] as cursor (counts destroyed here)
__global__ void fill_kernel(const int* __restrict__ ei, const int* __restrict__ offs,
                            int* __restrict__ counts, int* __restrict__ srcIdx) {
    int e = blockIdx.x * 256 + threadIdx.x;
    if (e >= EE) return;
    int r = ei[e];        // source (gathered from)
    int c = ei[EE + e];   // target (aggregated into)
    int old = atomicSub(&counts[c], 1);
    srcIdx[offs[c] + old - 1] = r;
}

// pack W1 into per-lane MFMA B-fragment order:
// dst[((kk*16+t)*64 + q*16 + l)*8 + jj] = bf16(W1[kk*32+q*8+jj][t*16+l])
__global__ void pack_w1(const float* __restrict__ W1, short* __restrict__ W1p) {
    int id = blockIdx.x * 256 + threadIdx.x;
    if (id >= INF * HIDF) return;
    int jj = id & 7, l = (id >> 3) & 15, q = (id >> 7) & 3, t = (id >> 9) & 15, kk = id >> 13;
    int k = kk * 32 + q * 8 + jj, n = t * 16 + l;
    W1p[id] = (short)f2bf(W1[k * HIDF + n]);
}

__global__ void pack_w2(const float* __restrict__ W2, short* __restrict__ W2p) {
    int id = blockIdx.x * 256 + threadIdx.x;
    if (id >= HIDF * OUTF) return;
    int jj = id & 7, l = (id >> 3) & 15, q = (id >> 7) & 3, t = (id >> 9) & 3, kk = id >> 11;
    int k = kk * 32 + q * 8 + jj, n = t * 16 + l;
    W2p[id] = (short)f2bf(W2[k * OUTF + n]);
}

// ---------------- fused MLP: h = relu(x@W1+b1)@W2+b2 ----------------
// writes z0 = bf16(dinv*h) and out = temp[0]*h
// GEMM1 x-access: K processed in 4 chunks of 128. Each chunk the block
// cooperatively loads the 64x128 f32 sub-tile with coalesced float4 loads
// (64 consecutive lanes = two full 512B row segments), converts to bf16,
// stages in LDS (row stride 272B == 16 mod 128 -> <=2-way bank aliasing,
// free), then waves read MFMA A-fragments via ds_read_b128. x is read ONCE
// per block, coalesced (was: per-lane 32B gathers in fragment order, 4x
// re-read -> 968 GB/s, 152us).

__global__ __launch_bounds__(256) void mlp_kernel(
    const float* __restrict__ x, const short* __restrict__ W1p,
    const short* __restrict__ W2p, const float* __restrict__ b1,
    const float* __restrict__ b2, const float* __restrict__ temp,
    const float* __restrict__ dinv,
    ushort_t* __restrict__ z0, float* __restrict__ out) {

    __shared__ __align__(16) short xlds[64][136];      // 17408 B
    __shared__ __align__(16) short hlds[64][HIDF + 8]; // 33792 B

    int tid = threadIdx.x;
    int wave = tid >> 6, lane = tid & 63;
    int l16 = lane & 15, quad = lane >> 4;
    int brow = blockIdx.x * 64;

    const floatx4 zf = {0.f, 0.f, 0.f, 0.f};
    floatx4 acc[4][4];
#pragma unroll
    for (int mi = 0; mi < 4; mi++)
#pragma unroll
        for (int j = 0; j < 4; j++) acc[mi][j] = zf;

    // GEMM1: rows [brow,brow+64) x cols [wave*64, wave*64+64), K=512
    for (int kc = 0; kc < 4; kc++) {
        __syncthreads();   // xlds reuse guard (no-op cost on kc=0)
        // stage 64x128 f32 -> bf16 LDS, coalesced
#pragma unroll
        for (int i = 0; i < 8; i++) {
            int id = i * 256 + tid;          // 0..2047 float4-slots
            int r = id >> 5;                 // tile row 0..63
            int c4 = id & 31;                // float4 col 0..31
            int row = brow + r;
            if (row > NN - 1) row = NN - 1;  // tail clamp (stores masked later)
            float4 f = *reinterpret_cast<const float4*>(
                x + (size_t)row * INF + kc * 128 + c4 * 4);
            uint2 u;
            u.x = (unsigned)f2bf(f.x) | ((unsigned)f2bf(f.y) << 16);
            u.y = (unsigned)f2bf(f.z) | ((unsigned)f2bf(f.w) << 16);
            *reinterpret_cast<uint2*>(&xlds[r][c4 * 4]) = u;
        }
        __syncthreads();
#pragma unroll
        for (int kk = 0; kk < 4; kk++) {
            int kg = kc * 4 + kk;            // global K-step 0..15
            short8 a[4];
#pragma unroll
            for (int mi = 0; mi < 4; mi++)
                a[mi] = *reinterpret_cast<const short8*>(
                    &xlds[mi * 16 + l16][kk * 32 + quad * 8]);
            short8 b[4];
#pragma unroll
            for (int j = 0; j < 4; j++) {
                int t = wave * 4 + j;
                b[j] = *reinterpret_cast<const short8*>(
                    W1p + (((size_t)(kg * 16 + t) * 64 + quad * 16 + l16) << 3));
            }
#pragma unroll
            for (int mi = 0; mi < 4; mi++)
#pragma unroll
                for (int j = 0; j < 4; j++)
                    acc[mi][j] = __builtin_amdgcn_mfma_f32_16x16x32_bf16(
                        a[mi], b[j], acc[mi][j], 0, 0, 0);
        }
    }

    // bias + relu -> LDS (bf16), C-layout: D[row=quad*4+r][col=l16]
#pragma unroll
    for (int j = 0; j < 4; j++) {
        float bj = b1[wave * 64 + j * 16 + l16];
#pragma unroll
        for (int mi = 0; mi < 4; mi++)
#pragma unroll
            for (int r = 0; r < 4; r++) {
                float v = acc[mi][j][r] + bj;
                v = fmaxf(v, 0.f);
                hlds[mi * 16 + quad * 4 + r][wave * 64 + j * 16 + l16] = (short)f2bf(v);
            }
    }
    __syncthreads();

    // GEMM2: wave handles rows [wave*16, wave*16+16) x 64 out cols, K=256
    floatx4 acc2[4];
#pragma unroll
    for (int j = 0; j < 4; j++) acc2[j] = zf;

#pragma unroll
    for (int kk = 0; kk < 8; kk++) {
        short8 a2 = *reinterpret_cast<const short8*>(&hlds[wave * 16 + l16][kk * 32 + quad * 8]);
#pragma unroll
        for (int j = 0; j < 4; j++) {
            short8 bb = *reinterpret_cast<const short8*>(
                W2p + (((size_t)(kk * 4 + j) * 64 + quad * 16 + l16) << 3));
            acc2[j] = __builtin_amdgcn_mfma_f32_16x16x32_bf16(a2, bb, acc2[j], 0, 0, 0);
        }
    }

    float t0 = temp[0];
#pragma unroll
    for (int j = 0; j < 4; j++) {
        float bb = b2[j * 16 + l16];
#pragma unroll
        for (int r = 0; r < 4; r++) {
            int row = brow + wave * 16 + quad * 4 + r;
            if (row < NN) {
                float v = acc2[j][r] + bb;
                size_t o = (size_t)row * 64 + j * 16 + l16;
                out[o] = t0 * v;
                z0[o] = f2bf(dinv[row] * v);
            }
        }
    }
}

// ---------------- propagation: one wave per target node ----------------
// Wide-gather layout: lane = (g, q), g = lane>>3 picks one of 8 edges per
// load instruction, q = lane&7 owns features q*8..q*8+7 (16B of bf16).
// Each lane loads dwordx4 (16B) per edge -> 8 edges per wave per VMEM instr,
// 2-deep unroll -> 2KB outstanding per wave.
// acc = z[self] + sum z[src]; cn = dinv*acc; hid += temp[k]*cn;
// z' = bf16(dinv*cn).

#define BLO(u) __uint_as_float((u) << 16)
#define BHI(u) __uint_as_float((u) & 0xFFFF0000u)
#define ACC8(v)                      \
    do {                             \
        a0 += BLO((v).x);            \
        a1 += BHI((v).x);            \
        a2 += BLO((v).y);            \
        a3 += BHI((v).y);            \
        a4 += BLO((v).z);            \
        a5 += BHI((v).z);            \
        a6 += BLO((v).w);            \
        a7 += BHI((v).w);            \
    } while (0)

__global__ __launch_bounds__(256, 8) void prop_kernel(
    const int* __restrict__ srcIdx, const int* __restrict__ offs,
    const float* __restrict__ dinv, const ushort_t* __restrict__ z,
    ushort_t* __restrict__ zn, float* __restrict__ hid,
    const float* __restrict__ temp, int k, int write_z) {

    int node = blockIdx.x * 4 + (threadIdx.x >> 6);   // NN = 4*25000 exactly
    int lane = threadIdx.x & 63;
    int g = lane >> 3;   // edge slot within the 8-edge group
    int q = lane & 7;    // feature octet

    int beg = __builtin_amdgcn_readfirstlane(offs[node]);
    int end = __builtin_amdgcn_readfirstlane(offs[node + 1]);

    float a0 = 0.f, a1 = 0.f, a2 = 0.f, a3 = 0.f;
    float a4 = 0.f, a5 = 0.f, a6 = 0.f, a7 = 0.f;

    // self-loop term: whole wave loads (line broadcast), only group 0 adds
    {
        uint4 v = reinterpret_cast<const uint4*>(z + ((size_t)node << 6))[q];
        if (g == 0) ACC8(v);
    }

    int e = beg;
    // main loop: 16 edges per iteration, 2 independent 16B gathers in flight
    for (; e + 16 <= end; e += 16) {
        int s0 = srcIdx[e + g];
        int s1 = srcIdx[e + 8 + g];
        uint4 v0 = reinterpret_cast<const uint4*>(z + ((size_t)s0 << 6))[q];
        uint4 v1 = reinterpret_cast<const uint4*>(z + ((size_t)s1 << 6))[q];
        ACC8(v0);
        ACC8(v1);
    }
    // tail: 8 edges at a time, clamp+predicate
    for (; e < end; e += 8) {
        int ee = e + g;
        int cl = (ee < end) ? ee : (end - 1);
        int s = srcIdx[cl];
        uint4 v = reinterpret_cast<const uint4*>(z + ((size_t)s << 6))[q];
        if (ee < end) ACC8(v);
    }

    // butterfly reduce across the 8 edge-groups (lane bits 3,4,5)
#pragma unroll
    for (int m = 8; m < 64; m <<= 1) {
        a0 += __shfl_xor(a0, m);
        a1 += __shfl_xor(a1, m);
        a2 += __shfl_xor(a2, m);
        a3 += __shfl_xor(a3, m);
        a4 += __shfl_xor(a4, m);
        a5 += __shfl_xor(a5, m);
        a6 += __shfl_xor(a6, m);
        a7 += __shfl_xor(a7, m);
    }

    float dv = dinv[node];
    float tk = temp[k];
    float c0 = dv * a0, c1 = dv * a1, c2 = dv * a2, c3 = dv * a3;
    float c4 = dv * a4, c5 = dv * a5, c6 = dv * a6, c7 = dv * a7;

    if (g == 0) {
        float* hp = hid + ((size_t)node << 6) + q * 8;
        float4 h0 = *reinterpret_cast<float4*>(hp);
        float4 h1 = *reinterpret_cast<float4*>(hp + 4);
        h0.x += tk * c0; h0.y += tk * c1; h0.z += tk * c2; h0.w += tk * c3;
        h1.x += tk * c4; h1.y += tk * c5; h1.z += tk * c6; h1.w += tk * c7;
        *reinterpret_cast<float4*>(hp) = h0;
        *reinterpret_cast<float4*>(hp + 4) = h1;
        if (write_z) {
            uint4 u;
            u.x = (unsigned)f2bf(dv * c0) | ((unsigned)f2bf(dv * c1) << 16);
            u.y = (unsigned)f2bf(dv * c2) | ((unsigned)f2bf(dv * c3) << 16);
            u.z = (unsigned)f2bf(dv * c4) | ((unsigned)f2bf(dv * c5) << 16);
            u.w = (unsigned)f2bf(dv * c6) | ((unsigned)f2bf(dv * c7) << 16);
            reinterpret_cast<uint4*>(zn + ((size_t)node << 6))[q] = u;
        }
    }
}

// ---------------- launch ----------------

extern "C" void kernel_launch(void* const* d_in, const int* in_sizes, int n_in,
                              void* d_out, int out_size, void* d_ws, size_t ws_size,
                              hipStream_t stream) {
    const float* x    = (const float*)d_in[0];
    const int*   ei   = (const int*)d_in[1];   // [2,E] int32 (harness converts int64)
    const float* W1   = (const float*)d_in[2];
    const float* b1   = (const float*)d_in[3];
    const float* W2   = (const float*)d_in[4];
    const float* b2   = (const float*)d_in[5];
    const float* temp = (const float*)d_in[6];
    float* out = (float*)d_out;

    char* p = (char*)d_ws;
    auto carve = [&](size_t bytes) -> char* {
        char* r = p;
        p += (bytes + 255) & ~(size_t)255;
        return r;
    };
    ushort_t* zA   = (ushort_t*)carve(sizeof(ushort_t) * (size_t)NN * 64);
    ushort_t* zB   = (ushort_t*)carve(sizeof(ushort_t) * (size_t)NN * 64);
    int* srcIdx    = (int*)carve(sizeof(int) * (size_t)EE);
    int* counts    = (int*)carve(sizeof(int) * NN);
    int* offs      = (int*)carve(sizeof(int) * (NN + 1));
    int* partial   = (int*)carve(sizeof(int) * 512);
    float* dinv    = (float*)carve(sizeof(float) * NN);
    short* W1p     = (short*)carve(sizeof(short) * INF * HIDF);
    short* W2p     = (short*)carve(sizeof(short) * HIDF * OUTF);

    const int NB = (NN + 255) / 256;      // 391

    zero_kernel<<<NB, 256, 0, stream>>>(counts, NN);
    pack_w1<<<(INF * HIDF + 255) / 256, 256, 0, stream>>>(W1, W1p);
    pack_w2<<<(HIDF * OUTF + 255) / 256, 256, 0, stream>>>(W2, W2p);

    count_kernel<<<EE / 256, 256, 0, stream>>>(ei, counts);
    dinv_kernel<<<NB, 256, 0, stream>>>(counts, dinv);
    scan1<<<NB, 256, 0, stream>>>(counts, offs, partial);
    scan2<<<1, 512, 0, stream>>>(partial, NB);
    scan3<<<(NN + 256) / 256, 256, 0, stream>>>(offs, partial);
    fill_kernel<<<EE / 256, 256, 0, stream>>>(ei, offs, counts, srcIdx);

    mlp_kernel<<<(NN + 63) / 64, 256, 0, stream>>>(x, W1p, W2p, b1, b2, temp, dinv, zA, out);

    ushort_t* a = zA;
    ushort_t* b = zB;
    for (int k = 1; k <= KSTEPS; k++) {
        prop_kernel<<<NN / 4, 256, 0, stream>>>(srcIdx, offs, dinv, a, b, out, temp, k,
                                                (k < KSTEPS) ? 1 : 0);
        ushort_t* t = a; a = b; b = t;
    }
}

// Round 7
// 1262.233 us; speedup vs baseline: 1.4906x; 1.0045x over previous
//
#include <hip/hip_runtime.h>
#include <hip/hip_bf16.h>

#define NN   100000
#define EE   3200000
#define INF  512
#define HIDF 256
#define OUTF 64
#define KSTEPS 10

// XCD-partitioned fill: 8 target regions x 1250 edge slices
#define NREG   8
#define REGW   (NN / NREG)      // 12500 nodes per region
#define SLICE_E 2560
#define NSLICE (EE / SLICE_E)   // 1250

typedef __attribute__((ext_vector_type(8))) short short8;
typedef __attribute__((ext_vector_type(4))) float floatx4;
typedef unsigned short ushort_t;

static __device__ inline short bf2s(__hip_bfloat16 h) {
    return __builtin_bit_cast(short, h);
}

// manual round-to-nearest-even f32 -> bf16 (finite inputs)
static __device__ inline unsigned short f2bf(float f) {
    unsigned u = __float_as_uint(f);
    unsigned r = (u + 0x7FFFu + ((u >> 16) & 1u)) >> 16;
    return (unsigned short)r;
}

static __device__ inline float b2f(unsigned short u) {
    return __uint_as_float(((unsigned)u) << 16);
}

// ---------------- setup kernels ----------------

__global__ void zero_kernel(int* p, int n) {
    int i = blockIdx.x * 256 + threadIdx.x;
    if (i < n) p[i] = 0;
}

__global__ void count_kernel(const int* __restrict__ ei, int* __restrict__ counts) {
    int e = blockIdx.x * 256 + threadIdx.x;
    if (e < EE) atomicAdd(&counts[ei[EE + e]], 1);
}

__global__ void dinv_kernel(const int* __restrict__ counts, float* __restrict__ dinv) {
    int i = blockIdx.x * 256 + threadIdx.x;
    if (i < NN) dinv[i] = rsqrtf((float)(counts[i] + 1));  // +1 self loop
}

// chunk=256 exclusive scan, per-block
__global__ void scan1(const int* __restrict__ counts, int* __restrict__ offs,
                      int* __restrict__ partial) {
    __shared__ int s[256];
    int tid = threadIdx.x;
    int i = blockIdx.x * 256 + tid;
    int v = (i < NN) ? counts[i] : 0;
    s[tid] = v;
    __syncthreads();
    for (int d = 1; d < 256; d <<= 1) {
        int t = (tid >= d) ? s[tid - d] : 0;
        __syncthreads();
        s[tid] += t;
        __syncthreads();
    }
    if (i < NN) offs[i] = s[tid] - v;     // exclusive within block
    if (tid == 255) partial[blockIdx.x] = s[255];
}

__global__ void scan2(int* partial, int nblocks) {
    __shared__ int s[512];
    int tid = threadIdx.x;
    int v = (tid < nblocks) ? partial[tid] : 0;
    s[tid] = v;
    __syncthreads();
    for (int d = 1; d < 512; d <<= 1) {
        int t = (tid >= d) ? s[tid - d] : 0;
        __syncthreads();
        s[tid] += t;
        __syncthreads();
    }
    if (tid < nblocks) partial[tid] = s[tid] - v;  // exclusive block bases
}

__global__ void scan3(int* __restrict__ offs, const int* __restrict__ partial) {
    int i = blockIdx.x * 256 + threadIdx.x;
    if (i < NN) offs[i] += partial[i >> 8];
    else if (i == NN) offs[NN] = EE;
}

// XCD-partitioned countdown-fill. Block b = (slice = b>>3, region = b&7):
// scans slice's targets, processes only edges with target in its region
// (12500 nodes -> 1.6MB srcIdx window). Coverage: every (slice,region) pair
// processed exactly once -> correctness independent of block->XCD mapping.
// Perf: with round-robin dispatch, region r's writers all sit on XCD r ->
// the 16 scatter-writes per 64B line coalesce in that XCD's L2 (was 16x
// write amplification, 197MB -> ~13MB). Edge-stream reads non-temporal so
// they don't evict the dirty window. counts[] reused as cursor (destroyed).
__global__ __launch_bounds__(256) void fillx_kernel(
    const int* __restrict__ ei, const int* __restrict__ offs,
    int* __restrict__ counts, int* __restrict__ srcIdx) {
    int b = blockIdx.x;
    int r = b & 7;
    int slice = b >> 3;
    int lo = r * REGW, hi = lo + REGW;
    int base = slice * SLICE_E;
    for (int i = threadIdx.x; i < SLICE_E; i += 256) {
        int e = base + i;
        int c = __builtin_nontemporal_load(ei + EE + e);
        if (c >= lo && c < hi) {
            int src = __builtin_nontemporal_load(ei + e);
            int old = atomicSub(&counts[c], 1);
            srcIdx[offs[c] + old - 1] = src;
        }
    }
}

// pack W1 into per-lane MFMA B-fragment order:
// dst[((kk*16+t)*64 + q*16 + l)*8 + jj] = bf16(W1[kk*32+q*8+jj][t*16+l])
__global__ void pack_w1(const float* __restrict__ W1, short* __restrict__ W1p) {
    int id = blockIdx.x * 256 + threadIdx.x;
    if (id >= INF * HIDF) return;
    int jj = id & 7, l = (id >> 3) & 15, q = (id >> 7) & 3, t = (id >> 9) & 15, kk = id >> 13;
    int k = kk * 32 + q * 8 + jj, n = t * 16 + l;
    W1p[id] = (short)f2bf(W1[k * HIDF + n]);
}

__global__ void pack_w2(const float* __restrict__ W2, short* __restrict__ W2p) {
    int id = blockIdx.x * 256 + threadIdx.x;
    if (id >= HIDF * OUTF) return;
    int jj = id & 7, l = (id >> 3) & 15, q = (id >> 7) & 3, t = (id >> 9) & 3, kk = id >> 11;
    int k = kk * 32 + q * 8 + jj, n = t * 16 + l;
    W2p[id] = (short)f2bf(W2[k * OUTF + n]);
}

// ---------------- fused MLP: h = relu(x@W1+b1)@W2+b2 ----------------
// writes z0 = bf16(dinv*h) and out = temp[0]*h
// GEMM1 x-access: K in 4 chunks of 128; block cooperatively stages the
// 64x128 f32 sub-tile with coalesced float4 loads -> bf16 -> LDS, waves
// read MFMA A-fragments via ds_read_b128. x read once per block, coalesced.

__global__ __launch_bounds__(256) void mlp_kernel(
    const float* __restrict__ x, const short* __restrict__ W1p,
    const short* __restrict__ W2p, const float* __restrict__ b1,
    const float* __restrict__ b2, const float* __restrict__ temp,
    const float* __restrict__ dinv,
    ushort_t* __restrict__ z0, float* __restrict__ out) {

    __shared__ __align__(16) short xlds[64][136];      // 17408 B
    __shared__ __align__(16) short hlds[64][HIDF + 8]; // 33792 B

    int tid = threadIdx.x;
    int wave = tid >> 6, lane = tid & 63;
    int l16 = lane & 15, quad = lane >> 4;
    int brow = blockIdx.x * 64;

    const floatx4 zf = {0.f, 0.f, 0.f, 0.f};
    floatx4 acc[4][4];
#pragma unroll
    for (int mi = 0; mi < 4; mi++)
#pragma unroll
        for (int j = 0; j < 4; j++) acc[mi][j] = zf;

    // GEMM1: rows [brow,brow+64) x cols [wave*64, wave*64+64), K=512
    for (int kc = 0; kc < 4; kc++) {
        __syncthreads();   // xlds reuse guard (no-op cost on kc=0)
        // stage 64x128 f32 -> bf16 LDS, coalesced
#pragma unroll
        for (int i = 0; i < 8; i++) {
            int id = i * 256 + tid;          // 0..2047 float4-slots
            int r = id >> 5;                 // tile row 0..63
            int c4 = id & 31;                // float4 col 0..31
            int row = brow + r;
            if (row > NN - 1) row = NN - 1;  // tail clamp (stores masked later)
            float4 f = *reinterpret_cast<const float4*>(
                x + (size_t)row * INF + kc * 128 + c4 * 4);
            uint2 u;
            u.x = (unsigned)f2bf(f.x) | ((unsigned)f2bf(f.y) << 16);
            u.y = (unsigned)f2bf(f.z) | ((unsigned)f2bf(f.w) << 16);
            *reinterpret_cast<uint2*>(&xlds[r][c4 * 4]) = u;
        }
        __syncthreads();
#pragma unroll
        for (int kk = 0; kk < 4; kk++) {
            int kg = kc * 4 + kk;            // global K-step 0..15
            short8 a[4];
#pragma unroll
            for (int mi = 0; mi < 4; mi++)
                a[mi] = *reinterpret_cast<const short8*>(
                    &xlds[mi * 16 + l16][kk * 32 + quad * 8]);
            short8 b[4];
#pragma unroll
            for (int j = 0; j < 4; j++) {
                int t = wave * 4 + j;
                b[j] = *reinterpret_cast<const short8*>(
                    W1p + (((size_t)(kg * 16 + t) * 64 + quad * 16 + l16) << 3));
            }
#pragma unroll
            for (int mi = 0; mi < 4; mi++)
#pragma unroll
                for (int j = 0; j < 4; j++)
                    acc[mi][j] = __builtin_amdgcn_mfma_f32_16x16x32_bf16(
                        a[mi], b[j], acc[mi][j], 0, 0, 0);
        }
    }

    // bias + relu -> LDS (bf16), C-layout: D[row=quad*4+r][col=l16]
#pragma unroll
    for (int j = 0; j < 4; j++) {
        float bj = b1[wave * 64 + j * 16 + l16];
#pragma unroll
        for (int mi = 0; mi < 4; mi++)
#pragma unroll
            for (int r = 0; r < 4; r++) {
                float v = acc[mi][j][r] + bj;
                v = fmaxf(v, 0.f);
                hlds[mi * 16 + quad * 4 + r][wave * 64 + j * 16 + l16] = (short)f2bf(v);
            }
    }
    __syncthreads();

    // GEMM2: wave handles rows [wave*16, wave*16+16) x 64 out cols, K=256
    floatx4 acc2[4];
#pragma unroll
    for (int j = 0; j < 4; j++) acc2[j] = zf;

#pragma unroll
    for (int kk = 0; kk < 8; kk++) {
        short8 a2 = *reinterpret_cast<const short8*>(&hlds[wave * 16 + l16][kk * 32 + quad * 8]);
#pragma unroll
        for (int j = 0; j < 4; j++) {
            short8 bb = *reinterpret_cast<const short8*>(
                W2p + (((size_t)(kk * 4 + j) * 64 + quad * 16 + l16) << 3));
            acc2[j] = __builtin_amdgcn_mfma_f32_16x16x32_bf16(a2, bb, acc2[j], 0, 0, 0);
        }
    }

    float t0 = temp[0];
#pragma unroll
    for (int j = 0; j < 4; j++) {
        float bb = b2[j * 16 + l16];
#pragma unroll
        for (int r = 0; r < 4; r++) {
            int row = brow + wave * 16 + quad * 4 + r;
            if (row < NN) {
                float v = acc2[j][r] + bb;
                size_t o = (size_t)row * 64 + j * 16 + l16;
                out[o] = t0 * v;
                z0[o] = f2bf(dinv[row] * v);
            }
        }
    }
}

// ---------------- propagation: one wave per target node ----------------
// Wide-gather layout: lane = (g, q), g = lane>>3 picks one of 8 edges per
// load instruction, q = lane&7 owns features q*8..q*8+7 (16B of bf16).
// Each lane loads dwordx4 (16B) per edge -> 8 edges per wave per VMEM instr,
// 2-deep unroll -> 2KB outstanding per wave.
// acc = z[self] + sum z[src]; cn = dinv*acc; hid += temp[k]*cn;
// z' = bf16(dinv*cn).

#define BLO(u) __uint_as_float((u) << 16)
#define BHI(u) __uint_as_float((u) & 0xFFFF0000u)
#define ACC8(v)                      \
    do {                             \
        a0 += BLO((v).x);            \
        a1 += BHI((v).x);            \
        a2 += BLO((v).y);            \
        a3 += BHI((v).y);            \
        a4 += BLO((v).z);            \
        a5 += BHI((v).z);            \
        a6 += BLO((v).w);            \
        a7 += BHI((v).w);            \
    } while (0)

__global__ __launch_bounds__(256, 8) void prop_kernel(
    const int* __restrict__ srcIdx, const int* __restrict__ offs,
    const float* __restrict__ dinv, const ushort_t* __restrict__ z,
    ushort_t* __restrict__ zn, float* __restrict__ hid,
    const float* __restrict__ temp, int k, int write_z) {

    int node = blockIdx.x * 4 + (threadIdx.x >> 6);   // NN = 4*25000 exactly
    int lane = threadIdx.x & 63;
    int g = lane >> 3;   // edge slot within the 8-edge group
    int q = lane & 7;    // feature octet

    int beg = __builtin_amdgcn_readfirstlane(offs[node]);
    int end = __builtin_amdgcn_readfirstlane(offs[node + 1]);

    float a0 = 0.f, a1 = 0.f, a2 = 0.f, a3 = 0.f;
    float a4 = 0.f, a5 = 0.f, a6 = 0.f, a7 = 0.f;

    // self-loop term: whole wave loads (line broadcast), only group 0 adds
    {
        uint4 v = reinterpret_cast<const uint4*>(z + ((size_t)node << 6))[q];
        if (g == 0) ACC8(v);
    }

    int e = beg;
    // main loop: 16 edges per iteration, 2 independent 16B gathers in flight
    for (; e + 16 <= end; e += 16) {
        int s0 = srcIdx[e + g];
        int s1 = srcIdx[e + 8 + g];
        uint4 v0 = reinterpret_cast<const uint4*>(z + ((size_t)s0 << 6))[q];
        uint4 v1 = reinterpret_cast<const uint4*>(z + ((size_t)s1 << 6))[q];
        ACC8(v0);
        ACC8(v1);
    }
    // tail: 8 edges at a time, clamp+predicate
    for (; e < end; e += 8) {
        int ee = e + g;
        int cl = (ee < end) ? ee : (end - 1);
        int s = srcIdx[cl];
        uint4 v = reinterpret_cast<const uint4*>(z + ((size_t)s << 6))[q];
        if (ee < end) ACC8(v);
    }

    // butterfly reduce across the 8 edge-groups (lane bits 3,4,5)
#pragma unroll
    for (int m = 8; m < 64; m <<= 1) {
        a0 += __shfl_xor(a0, m);
        a1 += __shfl_xor(a1, m);
        a2 += __shfl_xor(a2, m);
        a3 += __shfl_xor(a3, m);
        a4 += __shfl_xor(a4, m);
        a5 += __shfl_xor(a5, m);
        a6 += __shfl_xor(a6, m);
        a7 += __shfl_xor(a7, m);
    }

    float dv = dinv[node];
    float tk = temp[k];
    float c0 = dv * a0, c1 = dv * a1, c2 = dv * a2, c3 = dv * a3;
    float c4 = dv * a4, c5 = dv * a5, c6 = dv * a6, c7 = dv * a7;

    if (g == 0) {
        float* hp = hid + ((size_t)node << 6) + q * 8;
        float4 h0 = *reinterpret_cast<float4*>(hp);
        float4 h1 = *reinterpret_cast<float4*>(hp + 4);
        h0.x += tk * c0; h0.y += tk * c1; h0.z += tk * c2; h0.w += tk * c3;
        h1.x += tk * c4; h1.y += tk * c5; h1.z += tk * c6; h1.w += tk * c7;
        *reinterpret_cast<float4*>(hp) = h0;
        *reinterpret_cast<float4*>(hp + 4) = h1;
        if (write_z) {
            uint4 u;
            u.x = (unsigned)f2bf(dv * c0) | ((unsigned)f2bf(dv * c1) << 16);
            u.y = (unsigned)f2bf(dv * c2) | ((unsigned)f2bf(dv * c3) << 16);
            u.z = (unsigned)f2bf(dv * c4) | ((unsigned)f2bf(dv * c5) << 16);
            u.w = (unsigned)f2bf(dv * c6) | ((unsigned)f2bf(dv * c7) << 16);
            reinterpret_cast<uint4*>(zn + ((size_t)node << 6))[q] = u;
        }
    }
}

// ---------------- launch ----------------

extern "C" void kernel_launch(void* const* d_in, const int* in_sizes, int n_in,
                              void* d_out, int out_size, void* d_ws, size_t ws_size,
                              hipStream_t stream) {
    const float* x    = (const float*)d_in[0];
    const int*   ei   = (const int*)d_in[1];   // [2,E] int32 (harness converts int64)
    const float* W1   = (const float*)d_in[2];
    const float* b1   = (const float*)d_in[3];
    const float* W2   = (const float*)d_in[4];
    const float* b2   = (const float*)d_in[5];
    const float* temp = (const float*)d_in[6];
    float* out = (float*)d_out;

    char* p = (char*)d_ws;
    auto carve = [&](size_t bytes) -> char* {
        char* r = p;
        p += (bytes + 255) & ~(size_t)255;
        return r;
    };
    ushort_t* zA   = (ushort_t*)carve(sizeof(ushort_t) * (size_t)NN * 64);
    ushort_t* zB   = (ushort_t*)carve(sizeof(ushort_t) * (size_t)NN * 64);
    int* srcIdx    = (int*)carve(sizeof(int) * (size_t)EE);
    int* counts    = (int*)carve(sizeof(int) * NN);
    int* offs      = (int*)carve(sizeof(int) * (NN + 1));
    int* partial   = (int*)carve(sizeof(int) * 512);
    float* dinv    = (float*)carve(sizeof(float) * NN);
    short* W1p     = (short*)carve(sizeof(short) * INF * HIDF);
    short* W2p     = (short*)carve(sizeof(short) * HIDF * OUTF);

    const int NB = (NN + 255) / 256;      // 391

    zero_kernel<<<NB, 256, 0, stream>>>(counts, NN);
    pack_w1<<<(INF * HIDF + 255) / 256, 256, 0, stream>>>(W1, W1p);
    pack_w2<<<(HIDF * OUTF + 255) / 256, 256, 0, stream>>>(W2, W2p);

    count_kernel<<<EE / 256, 256, 0, stream>>>(ei, counts);
    dinv_kernel<<<NB, 256, 0, stream>>>(counts, dinv);
    scan1<<<NB, 256, 0, stream>>>(counts, offs, partial);
    scan2<<<1, 512, 0, stream>>>(partial, NB);
    scan3<<<(NN + 256) / 256, 256, 0, stream>>>(offs, partial);
    fillx_kernel<<<NSLICE * NREG, 256, 0, stream>>>(ei, offs, counts, srcIdx);

    mlp_kernel<<<(NN + 63) / 64, 256, 0, stream>>>(x, W1p, W2p, b1, b2, temp, dinv, zA, out);

    ushort_t* a = zA;
    ushort_t* b = zB;
    for (int k = 1; k <= KSTEPS; k++) {
        prop_kernel<<<NN / 4, 256, 0, stream>>>(srcIdx, offs, dinv, a, b, out, temp, k,
                                                (k < KSTEPS) ? 1 : 0);
        ushort_t* t = a; a = b; b = t;
    }
}